// Round 1
// baseline (5814.342 us; speedup 1.0000x reference)
//
#include <hip/hip_runtime.h>
#include <hip/hip_fp16.h>

typedef unsigned int u32;
typedef unsigned short u16;
typedef unsigned long long u64;

#define BB 64
#define TT 512
#define FF 128
#define HH 512
#define G4 2048  // 4*H

typedef _Float16 f16x8 __attribute__((ext_vector_type(8)));
typedef float f32x4 __attribute__((ext_vector_type(4)));

union UH2 { u32 u; __half2 h; };
__device__ inline __half2 u2h(u32 u) { UH2 t; t.u = u; return t.h; }

__device__ inline float sigm(float x) { return 1.0f / (1.0f + __expf(-x)); }
__device__ inline float tanh_fast(float x) { return 2.0f / (1.0f + __expf(-2.0f * x)) - 1.0f; }

// ---------------------------------------------------------------------------
// Zero BN accumulators and barrier flags (ws is poisoned before each call).
// ---------------------------------------------------------------------------
__global__ __launch_bounds__(256) void zero_init(float* __restrict__ accum, u32* __restrict__ cnt)
{
    int tid = threadIdx.x;
    for (int i = tid; i < 2048; i += 256) accum[i] = 0.0f;
    for (int i = tid; i < 2048; i += 256) cnt[i] = 0u;
}

// ---------------------------------------------------------------------------
// MFMA f16 GEMM: C(f16)[M,2048] = A[M,K] @ B[K,2048] + bias.
// BM=BN=128, BK=32, 256 threads (4 waves in 2x2), 4x4 16x16x32 tiles/wave.
// ---------------------------------------------------------------------------
template <bool A_HALF, bool AFFINE>
__global__ __launch_bounds__(256) void gemm_mfma(
    const void* __restrict__ Av, const float* __restrict__ Bw,
    const float* __restrict__ bias, const float* __restrict__ sc,
    const float* __restrict__ tr, __half* __restrict__ C, int K)
{
    __shared__ _Float16 sA[128 * 40];
    __shared__ _Float16 sB[128 * 40];
    const int tid = threadIdx.x;
    const int bn = blockIdx.x << 7;
    const int bm = blockIdx.y << 7;
    const int w = tid >> 6, l = tid & 63;
    const int mq = w >> 1, nq = w & 1;
    const int am = l & 15, kg = l >> 4;

    const _Float16* apb = sA + (mq * 64 + am) * 40 + kg * 8;
    const _Float16* bpb = sB + (nq * 64 + am) * 40 + kg * 8;

    const int ar = tid >> 1, akc = (tid & 1) * 16;
    const int bnn = tid & 127, bkr = (tid >> 7) * 16;

    f32x4 acc[4][4];
#pragma unroll
    for (int i = 0; i < 4; ++i)
#pragma unroll
        for (int j = 0; j < 4; ++j) acc[i][j] = (f32x4){0.f, 0.f, 0.f, 0.f};

    for (int k0 = 0; k0 < K; k0 += 32) {
        {
            float av[16];
            if constexpr (A_HALF) {
                const __half* Ap = (const __half*)Av + (size_t)(bm + ar) * K + k0 + akc;
                __half tmp[16];
                *(uint4*)&tmp[0] = *(const uint4*)Ap;
                *(uint4*)&tmp[8] = *(const uint4*)(Ap + 8);
#pragma unroll
                for (int i = 0; i < 16; ++i) av[i] = __half2float(tmp[i]);
            } else {
                const float* Ap = (const float*)Av + (size_t)(bm + ar) * K + k0 + akc;
#pragma unroll
                for (int i = 0; i < 16; i += 4) {
                    float4 v = *(const float4*)(Ap + i);
                    av[i] = v.x; av[i + 1] = v.y; av[i + 2] = v.z; av[i + 3] = v.w;
                }
            }
            if constexpr (AFFINE) {
#pragma unroll
                for (int i = 0; i < 16; ++i) av[i] = av[i] * sc[k0 + akc + i] + tr[k0 + akc + i];
            }
            _Float16 st[16];
#pragma unroll
            for (int i = 0; i < 16; ++i) st[i] = (_Float16)av[i];
            *(f16x8*)(sA + ar * 40 + akc) = *(f16x8*)&st[0];
            *(f16x8*)(sA + ar * 40 + akc + 8) = *(f16x8*)&st[8];
        }
        {
            _Float16 st[16];
#pragma unroll
            for (int i = 0; i < 16; ++i)
                st[i] = (_Float16)Bw[(size_t)(k0 + bkr + i) * G4 + bn + bnn];
            *(f16x8*)(sB + bnn * 40 + bkr) = *(f16x8*)&st[0];
            *(f16x8*)(sB + bnn * 40 + bkr + 8) = *(f16x8*)&st[8];
        }
        __syncthreads();
        f16x8 af[4], bf[4];
#pragma unroll
        for (int i = 0; i < 4; ++i) af[i] = *(const f16x8*)(apb + i * 16 * 40);
#pragma unroll
        for (int j = 0; j < 4; ++j) bf[j] = *(const f16x8*)(bpb + j * 16 * 40);
#pragma unroll
        for (int i = 0; i < 4; ++i)
#pragma unroll
            for (int j = 0; j < 4; ++j)
                acc[i][j] = __builtin_amdgcn_mfma_f32_16x16x32_f16(af[i], bf[j], acc[i][j], 0, 0, 0);
        __syncthreads();
    }

#pragma unroll
    for (int i = 0; i < 4; ++i) {
        const int row0 = bm + mq * 64 + i * 16 + kg * 4;
#pragma unroll
        for (int j = 0; j < 4; ++j) {
            const int col = bn + nq * 64 + j * 16 + am;
            const float bv = bias[col];
#pragma unroll
            for (int r = 0; r < 4; ++r) {
                float v = acc[i][j][r] + bv;
                u32 hu = (u32)__half_as_ushort(__float2half(v));
                u32 hn = __shfl_down(hu, 1);
                if ((am & 1) == 0) {
                    u32 pk = hu | (hn << 16);
                    *(u32*)(C + (size_t)(row0 + r) * G4 + col) = pk;
                }
            }
        }
    }
}

// ---------------------------------------------------------------------------
// MFMA LSTM scan v6: PAIRED CHAINS. 16 blocks = 2 pair-groups (pg) x 8
// col-blocks (cb). Each block runs TWO independent 16-row recurrence chains
// (A = rows pg*32..+15, B = rows pg*32+16..+31) sharing the same 128-VGPR
// Wh slice. Software pipeline: the bypass gather for one chain is ISSUED
// before the other chain's compute phase and only drained at that phase's
// final __syncthreads, so its LLC round-trip hides under MFMA+update and
// overlaps with the h-store drain (in-order vmcnt => single max() wait).
// Intra-phase barriers are raw s_barrier + lgkmcnt(0)-only waits so the
// in-flight gather loads (vmcnt) are NOT drained mid-phase.
// Protocol per phase: poll 8 flags -> gather regs ... regs->LDS ->
// lgkm-barrier -> 32 MFMA -> zbuf -> lgkm-barrier -> update -> sc1 h store
// -> full syncthreads (drain) -> flag. BN stats fused (A+B share columns).
// ---------------------------------------------------------------------------
__global__ __launch_bounds__(512, 2) void lstm_scan_mfma(
    const __half* __restrict__ xW,   // [B*T, 2048] f16 (x@Wx + b)
    const float* __restrict__ Wh,    // [512, 2048] f32
    __half* __restrict__ hout,       // [B*T, 512] f16
    u32* __restrict__ flags,         // flags x 32-u32 spacing
    float* __restrict__ accum)       // [sum 512][sumsq 512]
{
    __shared__ _Float16 shh[8192];     // 16 KB frag-major: chunk ci=kt*64+kq*16+row
    __shared__ float zbuf[16 * 260];   // 16.25 KB: z [m16][gc 256 +4]

    const int tid = threadIdx.x;
    const int cb = blockIdx.x & 7;
    const int pg = blockIdx.x >> 3;    // pair group 0..1

    const int w = tid >> 6, l = tid & 63;
    const int am = l & 15, kq = l >> 4;

    // ---- one-time: wave's 32 Wh gate-cols -> 128 VGPRs per lane (shared by A,B)
    f16x8 bfr[2][16];
#pragma unroll
    for (int cg = 0; cg < 2; ++cg) {
        const int gcol = (w >> 1) * 512 + cb * 64 + (w & 1) * 32 + cg * 16 + am;
#pragma unroll
        for (int kt = 0; kt < 16; ++kt) {
            _Float16 tmp[8];
#pragma unroll
            for (int j = 0; j < 8; ++j)
                tmp[j] = (_Float16)Wh[(size_t)(kt * 32 + kq * 8 + j) * G4 + gcol];
            bfr[cg][kt] = *(f16x8*)tmp;
        }
    }

    // update identity: thread owns (row ub, hcols 2uh, 2uh+1)
    const int ub = tid >> 5, uh = tid & 31;
    const int rA = pg * 32, rB = pg * 32 + 16;
    const size_t growTA = (size_t)(rA + ub) * TT;
    const size_t growTB = (size_t)(rB + ub) * TT;
    const int cidA = pg * 2, cidB = pg * 2 + 1;

    const u32* pollpA = flags + (size_t)(cidA * 8 + (l & 7)) * 32;
    const u32* pollpB = flags + (size_t)(cidB * 8 + (l & 7)) * 32;
    u32* flagA = flags + (size_t)(cidA * 8 + cb) * 32;
    u32* flagB = flags + (size_t)(cidB * 8 + cb) * 32;

    float cA0 = 0.f, cA1 = 0.f, cB0 = 0.f, cB1 = 0.f;
    float ss0 = 0.f, ss1 = 0.f, sq0 = 0.f, sq1 = 0.f;
    u64 rgA[4], rgB[4];

    auto poll = [&](const u32* p, int tv) {
        while (!__all((int)(__hip_atomic_load(p, __ATOMIC_RELAXED,
                                              __HIP_MEMORY_SCOPE_AGENT) >= (u32)tv))) {}
    };

    // gather h(tm1)[16,512] of one chain into regs (bypass loads, issue-only;
    // vmcnt drained at the NEXT full __syncthreads)
    auto gather = [&](u64 (&rg)[4], int rbase, int tm1) {
#pragma unroll
        for (int hh = 0; hh < 2; ++hh) {
            int ci = hh * 512 + tid;
            int kt = ci >> 6, kq2 = (ci >> 4) & 3, row = ci & 15;
            const u64* src = (const u64*)(hout +
                ((size_t)(rbase + row) * TT + tm1) * HH + (kt * 4 + kq2) * 8);
            rg[2 * hh]     = __hip_atomic_load(src,     __ATOMIC_RELAXED, __HIP_MEMORY_SCOPE_AGENT);
            rg[2 * hh + 1] = __hip_atomic_load(src + 1, __ATOMIC_RELAXED, __HIP_MEMORY_SCOPE_AGENT);
        }
    };

    // regs -> frag-major LDS, lgkm-only barrier, 32 MFMA, z -> zbuf, barrier
    auto mfma_z = [&](const u64 (&rg)[4]) {
#pragma unroll
        for (int hh = 0; hh < 2; ++hh) {
            u64 pk2[2] = {rg[2 * hh], rg[2 * hh + 1]};
            *(uint4*)(shh + (hh * 512 + tid) * 8) = *(uint4*)pk2;
        }
        __builtin_amdgcn_sched_barrier(0);
        asm volatile("s_waitcnt lgkmcnt(0)" ::: "memory");
        __builtin_amdgcn_s_barrier();
        __builtin_amdgcn_sched_barrier(0);

        f32x4 a0 = {0.f, 0.f, 0.f, 0.f}, a1 = {0.f, 0.f, 0.f, 0.f};
#pragma unroll
        for (int kt = 0; kt < 16; ++kt) {
            f16x8 av = *(const f16x8*)(shh + kt * 512 + l * 8);
            a0 = __builtin_amdgcn_mfma_f32_16x16x32_f16(av, bfr[0][kt], a0, 0, 0, 0);
            a1 = __builtin_amdgcn_mfma_f32_16x16x32_f16(av, bfr[1][kt], a1, 0, 0, 0);
        }
        const int zc = (w >> 1) * 64 + (w & 1) * 32 + am;
#pragma unroll
        for (int r = 0; r < 4; ++r) {
            zbuf[(kq * 4 + r) * 260 + zc] = a0[r];
            zbuf[(kq * 4 + r) * 260 + zc + 16] = a1[r];
        }
        __builtin_amdgcn_sched_barrier(0);
        asm volatile("s_waitcnt lgkmcnt(0)" ::: "memory");
        __builtin_amdgcn_s_barrier();
        __builtin_amdgcn_sched_barrier(0);
    };

    // gate update for 2 cells + bypass h store (flag comes after caller's sync)
    auto upd = [&](u32 xi, u32 xf, u32 xg, u32 xo, bool addz,
                   float& c0, float& c1, size_t growT_, int t_) {
        __half2 hxi = u2h(xi), hxf = u2h(xf), hxg = u2h(xg), hxo = u2h(xo);
        float zi0 = __low2float(hxi), zi1 = __high2float(hxi);
        float zf0 = __low2float(hxf), zf1 = __high2float(hxf);
        float zg0 = __low2float(hxg), zg1 = __high2float(hxg);
        float zo0 = __low2float(hxo), zo1 = __high2float(hxo);
        if (addz) {
            const float* zr = zbuf + ub * 260 + 2 * uh;
            zi0 += zr[0];   zi1 += zr[1];
            zf0 += zr[64];  zf1 += zr[65];
            zg0 += zr[128]; zg1 += zr[129];
            zo0 += zr[192]; zo1 += zr[193];
        }
        float i0 = sigm(zi0), f0 = sigm(zf0), g0 = tanh_fast(zg0), o0 = sigm(zo0);
        float i1 = sigm(zi1), f1 = sigm(zf1), g1 = tanh_fast(zg1), o1 = sigm(zo1);
        c0 = f0 * c0 + i0 * g0;
        c1 = f1 * c1 + i1 * g1;
        float h0 = o0 * tanh_fast(c0);
        float h1 = o1 * tanh_fast(c1);
        ss0 += h0; sq0 += h0 * h0; ss1 += h1; sq1 += h1 * h1;
        u32 pk = (u32)__half_as_ushort(__float2half(h0)) |
                 ((u32)__half_as_ushort(__float2half(h1)) << 16);
        u32* dst = (u32*)(hout + (growT_ + t_) * HH + cb * 64) + uh;
        __hip_atomic_store(dst, pk, __ATOMIC_RELAXED, __HIP_MEMORY_SCOPE_AGENT);
    };

    // ---- t = 0: no recurrent term ----
    {
        const u32* xpA = (const u32*)(xW + growTA * G4) + cb * 32 + uh;
        u32 xiA = xpA[0], xfA = xpA[256], xgA = xpA[512], xoA = xpA[768];
        const u32* xpB = (const u32*)(xW + growTB * G4) + cb * 32 + uh;
        u32 xiB = xpB[0], xfB = xpB[256], xgB = xpB[512], xoB = xpB[768];
        upd(xiA, xfA, xgA, xoA, false, cA0, cA1, growTA, 0);
        __syncthreads();
        if (tid == 0)
            __hip_atomic_store(flagA, 1u, __ATOMIC_RELAXED, __HIP_MEMORY_SCOPE_AGENT);
        upd(xiB, xfB, xgB, xoB, false, cB0, cB1, growTB, 0);
        __syncthreads();
        if (tid == 0)
            __hip_atomic_store(flagB, 1u, __ATOMIC_RELAXED, __HIP_MEMORY_SCOPE_AGENT);
    }
    // prime pipeline: gather hA(0)
    poll(pollpA, 1);
    gather(rgA, rA, 0);

    for (int t = 1; t < TT; ++t) {
        // xW prefetch for phase A (cached loads, hidden under poll/gather)
        const u32* xpA = (const u32*)(xW + (growTA + t) * G4) + cb * 32 + uh;
        u32 xiA = xpA[0], xfA = xpA[256], xgA = xpA[512], xoA = xpA[768];

        // issue B's gather now; its latency hides under phase A's compute
        poll(pollpB, t);
        gather(rgB, rB, t - 1);

        // ---- phase A (step t) ----
        mfma_z(rgA);
        upd(xiA, xfA, xgA, xoA, true, cA0, cA1, growTA, t);
        __syncthreads();   // drains h stores AND (already-landed) gatherB loads
        if (tid == 0)
            __hip_atomic_store(flagA, (u32)(t + 1), __ATOMIC_RELAXED, __HIP_MEMORY_SCOPE_AGENT);

        // xW prefetch for phase B + issue A's next gather (hides under phase B)
        const u32* xpB = (const u32*)(xW + (growTB + t) * G4) + cb * 32 + uh;
        u32 xiB = xpB[0], xfB = xpB[256], xgB = xpB[512], xoB = xpB[768];
        if (t + 1 < TT) {
            poll(pollpA, t + 1);
            gather(rgA, rA, t);
        }

        // ---- phase B (step t) ----
        mfma_z(rgB);
        upd(xiB, xfB, xgB, xoB, true, cB0, cB1, growTB, t);
        __syncthreads();
        if (tid == 0)
            __hip_atomic_store(flagB, (u32)(t + 1), __ATOMIC_RELAXED, __HIP_MEMORY_SCOPE_AGENT);
    }

    // ---- fused BN stats (A and B share the same h-columns per thread) ----
    float* red = zbuf;
    red[ub * 64 + 2 * uh] = ss0;
    red[ub * 64 + 2 * uh + 1] = ss1;
    __syncthreads();
    if (tid < 64) {
        float s = 0.f;
#pragma unroll
        for (int b = 0; b < 16; ++b) s += red[b * 64 + tid];
        atomicAdd(&accum[cb * 64 + tid], s);
    }
    __syncthreads();
    red[ub * 64 + 2 * uh] = sq0;
    red[ub * 64 + 2 * uh + 1] = sq1;
    __syncthreads();
    if (tid < 64) {
        float s = 0.f;
#pragma unroll
        for (int b = 0; b < 16; ++b) s += red[b * 64 + tid];
        atomicAdd(&accum[HH + cb * 64 + tid], s);
    }
}

__global__ __launch_bounds__(512) void bn_finalize(
    const float* __restrict__ accum, const float* __restrict__ gamma,
    const float* __restrict__ beta, float* __restrict__ s, float* __restrict__ t)
{
    int j = threadIdx.x;
    const float inv = 1.0f / (float)(BB * TT);
    float m = accum[j] * inv;
    float v = accum[HH + j] * inv - m * m;
    float scv = gamma[j] * rsqrtf(v + 1e-5f);
    s[j] = scv;
    t[j] = beta[j] - m * scv;
}

// ---------------------------------------------------------------------------
// Head: out[m] = relu(bn(h2[m,:]) @ Wd1 + bd1) @ Wd2 + bd2
// ---------------------------------------------------------------------------
__global__ __launch_bounds__(256) void head_kernel(
    const __half* __restrict__ h2, const float* __restrict__ s2,
    const float* __restrict__ t2, const float* __restrict__ Wd1,
    const float* __restrict__ bd1, const float* __restrict__ Wd2,
    const float* __restrict__ bd2, float* __restrict__ out)
{
    const int tid = threadIdx.x;
    const int j = tid & 15;
    const int row = blockIdx.x * 16 + (tid >> 4);
    const __half* hr = h2 + (size_t)row * HH;
    float acc = 0.0f;
    for (int k = 0; k < HH; ++k) {
        float a = __half2float(hr[k]) * s2[k] + t2[k];
        acc += a * Wd1[k * 16 + j];
    }
    float r = fmaxf(acc + bd1[j], 0.0f);
    float v = r * Wd2[j];
#pragma unroll
    for (int off = 8; off; off >>= 1) v += __shfl_down(v, off, 16);
    if (j == 0) out[row] = v + bd2[0];
}

// ---------------------------------------------------------------------------
extern "C" void kernel_launch(void* const* d_in, const int* in_sizes, int n_in,
                              void* d_out, int out_size, void* d_ws, size_t ws_size,
                              hipStream_t stream)
{
    const float* x   = (const float*)d_in[0];
    const float* Wx1 = (const float*)d_in[1];
    const float* Wh1 = (const float*)d_in[2];
    const float* b1  = (const float*)d_in[3];
    const float* g1  = (const float*)d_in[4];
    const float* be1 = (const float*)d_in[5];
    const float* Wx2 = (const float*)d_in[6];
    const float* Wh2 = (const float*)d_in[7];
    const float* b2  = (const float*)d_in[8];
    const float* g2  = (const float*)d_in[9];
    const float* be2 = (const float*)d_in[10];
    const float* Wd1 = (const float*)d_in[11];
    const float* bd1 = (const float*)d_in[12];
    const float* Wd2 = (const float*)d_in[13];
    const float* bd2 = (const float*)d_in[14];
    float* out = (float*)d_out;

    char* ws = (char*)d_ws;
    __half* xW    = (__half*)(ws);                   // 128 MiB  [B*T, 2048]
    __half* h1    = (__half*)(ws + 134217728);       // 32 MiB   [B*T, 512]
    __half* h2    = (__half*)(ws + 167772160);       // 32 MiB
    float*  accum = (float*) (ws + 201326592);       // 2048 f32
    u32*    cnt   = (u32*)   (ws + 201334784);       // 2048 u32 barrier flags
    float*  s1    = (float*) (ws + 201342976);
    float*  t1    = s1 + HH;
    float*  s2    = t1 + HH;
    float*  t2    = s2 + HH;

    const int M = BB * TT;  // 32768

    zero_init<<<1, 256, 0, stream>>>(accum, cnt);

    gemm_mfma<false, false><<<dim3(16, M / 128), 256, 0, stream>>>(
        x, Wx1, b1, nullptr, nullptr, xW, FF);

    lstm_scan_mfma<<<16, 512, 0, stream>>>(xW, Wh1, h1, cnt, accum);
    bn_finalize<<<1, 512, 0, stream>>>(accum, g1, be1, s1, t1);

    gemm_mfma<true, true><<<dim3(16, M / 128), 256, 0, stream>>>(
        h1, Wx2, b2, s1, t1, xW, HH);

    lstm_scan_mfma<<<16, 512, 0, stream>>>(xW, Wh2, h2, cnt + 1024, accum + 1024);
    bn_finalize<<<1, 512, 0, stream>>>(accum + 1024, g2, be2, s2, t2);

    head_kernel<<<M / 16, 256, 0, stream>>>(h2, s2, t2, Wd1, bd1, Wd2, bd2, out);
}

// Round 4
// 3903.700 us; speedup vs baseline: 1.4894x; 1.4894x over previous
//
#include <hip/hip_runtime.h>
#include <hip/hip_fp16.h>

typedef unsigned int u32;
typedef unsigned short u16;
typedef unsigned long long u64;

#define BB 64
#define TT 512
#define FF 128
#define HH 512
#define G4 2048  // 4*H

#define SENT 0xFFFFFFFFu   // packed f16 NaN pair: unreachable for h in [-1,1]

typedef _Float16 f16x8 __attribute__((ext_vector_type(8)));
typedef float f32x4 __attribute__((ext_vector_type(4)));

union UH2 { u32 u; __half2 h; };
__device__ inline __half2 u2h(u32 u) { UH2 t; t.u = u; return t.h; }

__device__ inline float sigm(float x) { return 1.0f / (1.0f + __expf(-x)); }
__device__ inline float tanh_fast(float x) { return 2.0f / (1.0f + __expf(-2.0f * x)) - 1.0f; }

// ---------------------------------------------------------------------------
// Zero BN accumulators (ws is poisoned before each call).
// ---------------------------------------------------------------------------
__global__ __launch_bounds__(256) void zero_init(float* __restrict__ accum)
{
    int tid = threadIdx.x;
    for (int i = tid; i < 2048; i += 256) accum[i] = 0.0f;
}

// ---------------------------------------------------------------------------
// Fill h1+h2 (contiguous 64 MiB) with the sentinel word. Write-once dataflow:
// the LSTM scan's consumers poll gathered h data until every word != SENT.
// ---------------------------------------------------------------------------
__global__ __launch_bounds__(256) void sentinel_init(uint4* __restrict__ p, int n4)
{
    const uint4 s = {SENT, SENT, SENT, SENT};
    int idx = blockIdx.x * 256 + threadIdx.x;
    int stride = gridDim.x * 256;
    for (int i = idx; i < n4; i += stride) p[i] = s;
}

// ---------------------------------------------------------------------------
// MFMA f16 GEMM: C(f16)[M,2048] = A[M,K] @ B[K,2048] + bias.
// BM=BN=128, BK=32, 256 threads (4 waves in 2x2), 4x4 16x16x32 tiles/wave.
// ---------------------------------------------------------------------------
template <bool A_HALF, bool AFFINE>
__global__ __launch_bounds__(256) void gemm_mfma(
    const void* __restrict__ Av, const float* __restrict__ Bw,
    const float* __restrict__ bias, const float* __restrict__ sc,
    const float* __restrict__ tr, __half* __restrict__ C, int K)
{
    __shared__ _Float16 sA[128 * 40];
    __shared__ _Float16 sB[128 * 40];
    const int tid = threadIdx.x;
    const int bn = blockIdx.x << 7;
    const int bm = blockIdx.y << 7;
    const int w = tid >> 6, l = tid & 63;
    const int mq = w >> 1, nq = w & 1;
    const int am = l & 15, kg = l >> 4;

    const _Float16* apb = sA + (mq * 64 + am) * 40 + kg * 8;
    const _Float16* bpb = sB + (nq * 64 + am) * 40 + kg * 8;

    const int ar = tid >> 1, akc = (tid & 1) * 16;
    const int bnn = tid & 127, bkr = (tid >> 7) * 16;

    f32x4 acc[4][4];
#pragma unroll
    for (int i = 0; i < 4; ++i)
#pragma unroll
        for (int j = 0; j < 4; ++j) acc[i][j] = (f32x4){0.f, 0.f, 0.f, 0.f};

    for (int k0 = 0; k0 < K; k0 += 32) {
        {
            float av[16];
            if constexpr (A_HALF) {
                const __half* Ap = (const __half*)Av + (size_t)(bm + ar) * K + k0 + akc;
                __half tmp[16];
                *(uint4*)&tmp[0] = *(const uint4*)Ap;
                *(uint4*)&tmp[8] = *(const uint4*)(Ap + 8);
#pragma unroll
                for (int i = 0; i < 16; ++i) av[i] = __half2float(tmp[i]);
            } else {
                const float* Ap = (const float*)Av + (size_t)(bm + ar) * K + k0 + akc;
#pragma unroll
                for (int i = 0; i < 16; i += 4) {
                    float4 v = *(const float4*)(Ap + i);
                    av[i] = v.x; av[i + 1] = v.y; av[i + 2] = v.z; av[i + 3] = v.w;
                }
            }
            if constexpr (AFFINE) {
#pragma unroll
                for (int i = 0; i < 16; ++i) av[i] = av[i] * sc[k0 + akc + i] + tr[k0 + akc + i];
            }
            _Float16 st[16];
#pragma unroll
            for (int i = 0; i < 16; ++i) st[i] = (_Float16)av[i];
            *(f16x8*)(sA + ar * 40 + akc) = *(f16x8*)&st[0];
            *(f16x8*)(sA + ar * 40 + akc + 8) = *(f16x8*)&st[8];
        }
        {
            _Float16 st[16];
#pragma unroll
            for (int i = 0; i < 16; ++i)
                st[i] = (_Float16)Bw[(size_t)(k0 + bkr + i) * G4 + bn + bnn];
            *(f16x8*)(sB + bnn * 40 + bkr) = *(f16x8*)&st[0];
            *(f16x8*)(sB + bnn * 40 + bkr + 8) = *(f16x8*)&st[8];
        }
        __syncthreads();
        f16x8 af[4], bf[4];
#pragma unroll
        for (int i = 0; i < 4; ++i) af[i] = *(const f16x8*)(apb + i * 16 * 40);
#pragma unroll
        for (int j = 0; j < 4; ++j) bf[j] = *(const f16x8*)(bpb + j * 16 * 40);
#pragma unroll
        for (int i = 0; i < 4; ++i)
#pragma unroll
            for (int j = 0; j < 4; ++j)
                acc[i][j] = __builtin_amdgcn_mfma_f32_16x16x32_f16(af[i], bf[j], acc[i][j], 0, 0, 0);
        __syncthreads();
    }

#pragma unroll
    for (int i = 0; i < 4; ++i) {
        const int row0 = bm + mq * 64 + i * 16 + kg * 4;
#pragma unroll
        for (int j = 0; j < 4; ++j) {
            const int col = bn + nq * 64 + j * 16 + am;
            const float bv = bias[col];
#pragma unroll
            for (int r = 0; r < 4; ++r) {
                float v = acc[i][j][r] + bv;
                u32 hu = (u32)__half_as_ushort(__float2half(v));
                u32 hn = __shfl_down(hu, 1);
                if ((am & 1) == 0) {
                    u32 pk = hu | (hn << 16);
                    *(u32*)(C + (size_t)(row0 + r) * G4 + col) = pk;
                }
            }
        }
    }
}

// ---------------------------------------------------------------------------
// MFMA LSTM scan v8: SENTINEL DATAFLOW. Grid 32 = 4 chains (bg) x 8
// col-blocks (cb), 512 threads, v5 skeleton. hout is write-once per (t,word)
// and pre-filled with SENT (packed f16 NaNs, unreachable for h in [-1,1]),
// so consumers poll the gathered data itself until no word is SENT:
//   - no flags, no store drains, no fences, no cross-block barrier;
//   - each u32 is atomically sentinel or final -> validity is per-word;
//   - producers never block on consumers -> hang-proof by construction.
// Per step: poll-gather h[16,512] (self-validating agent-scope u64 loads)
// -> frag-major LDS -> sync -> 32 MFMA -> zbuf -> sync -> gate update
// (2 cells/thread) -> agent-scope h store (fire-and-forget). BN stats fused.
// ---------------------------------------------------------------------------
__global__ __launch_bounds__(512, 2) void lstm_scan_mfma(
    const __half* __restrict__ xW,   // [B*T, 2048] f16 (x@Wx + b)
    const float* __restrict__ Wh,    // [512, 2048] f32
    __half* __restrict__ hout,       // [B*T, 512] f16, pre-filled with SENT
    float* __restrict__ accum)       // [sum 512][sumsq 512]
{
    __shared__ _Float16 shh[8192];     // 16 KB frag-major: chunk ci=kt*64+kq*16+row
    __shared__ float zbuf[16 * 260];   // 16.25 KB: z [m16][gc 256 +4]

    const int tid = threadIdx.x;
    const int cb = blockIdx.x & 7;
    const int bg = blockIdx.x >> 3;

    const int w = tid >> 6, l = tid & 63;
    const int am = l & 15, kq = l >> 4;

    // ---- one-time: wave's 32 Wh gate-cols -> 128 VGPRs per lane ----
    f16x8 bfr[2][16];
#pragma unroll
    for (int cg = 0; cg < 2; ++cg) {
        const int gcol = (w >> 1) * 512 + cb * 64 + (w & 1) * 32 + cg * 16 + am;
#pragma unroll
        for (int kt = 0; kt < 16; ++kt) {
            _Float16 tmp[8];
#pragma unroll
            for (int j = 0; j < 8; ++j)
                tmp[j] = (_Float16)Wh[(size_t)(kt * 32 + kq * 8 + j) * G4 + gcol];
            bfr[cg][kt] = *(f16x8*)tmp;
        }
    }

    // update identity: thread owns (row ub, hcols 2uh, 2uh+1)
    const int ub = tid >> 5, uh = tid & 31;
    const size_t growT = (size_t)(bg * 16 + ub) * TT;

    // gather identity: 2 chunks of 16B, frag-major ci = hh*512+tid
    //   ci -> kt=ci>>6, kq2=(ci>>4)&3, row=ci&15
    const int ci0 = tid, ci1 = 512 + tid;
    const size_t go0 = (size_t)(bg * 16 + (ci0 & 15)) * TT * HH +
                       (((ci0 >> 6) * 4 + ((ci0 >> 4) & 3)) * 8);
    const size_t go1 = (size_t)(bg * 16 + (ci1 & 15)) * TT * HH +
                       (((ci1 >> 6) * 4 + ((ci1 >> 4) & 3)) * 8);

    float cst0 = 0.f, cst1 = 0.f;
    float ss0 = 0.f, ss1 = 0.f, sq0 = 0.f, sq1 = 0.f;

    for (int t = 0; t < TT; ++t) {
        // xW prefetch: 4 gates x packed pair (cached loads, in flight over poll)
        const u32* xp = (const u32*)(xW + (growT + t) * G4) + cb * 32 + uh;
        u32 xi = xp[0], xf = xp[256], xg = xp[512], xo = xp[768];

        if (t > 0) {
            // ---- self-validating poll-gather of h_{t-1}[16,512] ----
            const u64* src0 = (const u64*)(hout + go0 + (size_t)(t - 1) * HH);
            const u64* src1 = (const u64*)(hout + go1 + (size_t)(t - 1) * HH);
            u64 a, b, c, d;
            do {
                a = __hip_atomic_load(src0,     __ATOMIC_RELAXED, __HIP_MEMORY_SCOPE_AGENT);
                b = __hip_atomic_load(src0 + 1, __ATOMIC_RELAXED, __HIP_MEMORY_SCOPE_AGENT);
                c = __hip_atomic_load(src1,     __ATOMIC_RELAXED, __HIP_MEMORY_SCOPE_AGENT);
                d = __hip_atomic_load(src1 + 1, __ATOMIC_RELAXED, __HIP_MEMORY_SCOPE_AGENT);
            } while ((u32)a == SENT || (u32)(a >> 32) == SENT ||
                     (u32)b == SENT || (u32)(b >> 32) == SENT ||
                     (u32)c == SENT || (u32)(c >> 32) == SENT ||
                     (u32)d == SENT || (u32)(d >> 32) == SENT);
            u64 pk0[2] = {a, b};
            u64 pk1[2] = {c, d};
            *(uint4*)(shh + (size_t)ci0 * 8) = *(uint4*)pk0;
            *(uint4*)(shh + (size_t)ci1 * 8) = *(uint4*)pk1;
            __syncthreads();

            // ---- MFMA: 2 col-group chains, linear A-frag reads ----
            f32x4 a0 = {0.f, 0.f, 0.f, 0.f}, a1 = {0.f, 0.f, 0.f, 0.f};
#pragma unroll
            for (int kt = 0; kt < 16; ++kt) {
                f16x8 av = *(const f16x8*)(shh + kt * 512 + l * 8);
                a0 = __builtin_amdgcn_mfma_f32_16x16x32_f16(av, bfr[0][kt], a0, 0, 0, 0);
                a1 = __builtin_amdgcn_mfma_f32_16x16x32_f16(av, bfr[1][kt], a1, 0, 0, 0);
            }
            const int zc = (w >> 1) * 64 + (w & 1) * 32 + am;
#pragma unroll
            for (int r = 0; r < 4; ++r) {
                zbuf[(kq * 4 + r) * 260 + zc] = a0[r];
                zbuf[(kq * 4 + r) * 260 + zc + 16] = a1[r];
            }
            __syncthreads();
        }

        // ---- gate update: 2 cells per thread ----
        __half2 hxi = u2h(xi), hxf = u2h(xf), hxg = u2h(xg), hxo = u2h(xo);
        float zi0 = __low2float(hxi), zi1 = __high2float(hxi);
        float zf0 = __low2float(hxf), zf1 = __high2float(hxf);
        float zg0 = __low2float(hxg), zg1 = __high2float(hxg);
        float zo0 = __low2float(hxo), zo1 = __high2float(hxo);
        if (t > 0) {
            const float* zr = zbuf + ub * 260 + 2 * uh;
            zi0 += zr[0];   zi1 += zr[1];
            zf0 += zr[64];  zf1 += zr[65];
            zg0 += zr[128]; zg1 += zr[129];
            zo0 += zr[192]; zo1 += zr[193];
        }
        float i0 = sigm(zi0), f0 = sigm(zf0), g0 = tanh_fast(zg0), o0 = sigm(zo0);
        float i1 = sigm(zi1), f1 = sigm(zf1), g1 = tanh_fast(zg1), o1 = sigm(zo1);
        cst0 = f0 * cst0 + i0 * g0;
        cst1 = f1 * cst1 + i1 * g1;
        float h0 = o0 * tanh_fast(cst0);
        float h1 = o1 * tanh_fast(cst1);
        ss0 += h0; sq0 += h0 * h0; ss1 += h1; sq1 += h1 * h1;

        // fire-and-forget: the stored word itself announces completion
        u32 pk = (u32)__half_as_ushort(__float2half(h0)) |
                 ((u32)__half_as_ushort(__float2half(h1)) << 16);
        u32* dst = (u32*)(hout + (growT + t) * HH + cb * 64) + uh;
        __hip_atomic_store(dst, pk, __ATOMIC_RELAXED, __HIP_MEMORY_SCOPE_AGENT);
    }

    // ---- fused BN stats ----
    __syncthreads();   // all waves done with zbuf before reuse as reduction buf
    float* red = zbuf;
    red[ub * 64 + 2 * uh] = ss0;
    red[ub * 64 + 2 * uh + 1] = ss1;
    __syncthreads();
    if (tid < 64) {
        float s = 0.f;
#pragma unroll
        for (int b = 0; b < 16; ++b) s += red[b * 64 + tid];
        atomicAdd(&accum[cb * 64 + tid], s);
    }
    __syncthreads();
    red[ub * 64 + 2 * uh] = sq0;
    red[ub * 64 + 2 * uh + 1] = sq1;
    __syncthreads();
    if (tid < 64) {
        float s = 0.f;
#pragma unroll
        for (int b = 0; b < 16; ++b) s += red[b * 64 + tid];
        atomicAdd(&accum[HH + cb * 64 + tid], s);
    }
}

__global__ __launch_bounds__(512) void bn_finalize(
    const float* __restrict__ accum, const float* __restrict__ gamma,
    const float* __restrict__ beta, float* __restrict__ s, float* __restrict__ t)
{
    int j = threadIdx.x;
    const float inv = 1.0f / (float)(BB * TT);
    float m = accum[j] * inv;
    float v = accum[HH + j] * inv - m * m;
    float scv = gamma[j] * rsqrtf(v + 1e-5f);
    s[j] = scv;
    t[j] = beta[j] - m * scv;
}

// ---------------------------------------------------------------------------
// Head: out[m] = relu(bn(h2[m,:]) @ Wd1 + bd1) @ Wd2 + bd2
// ---------------------------------------------------------------------------
__global__ __launch_bounds__(256) void head_kernel(
    const __half* __restrict__ h2, const float* __restrict__ s2,
    const float* __restrict__ t2, const float* __restrict__ Wd1,
    const float* __restrict__ bd1, const float* __restrict__ Wd2,
    const float* __restrict__ bd2, float* __restrict__ out)
{
    const int tid = threadIdx.x;
    const int j = tid & 15;
    const int row = blockIdx.x * 16 + (tid >> 4);
    const __half* hr = h2 + (size_t)row * HH;
    float acc = 0.0f;
    for (int k = 0; k < HH; ++k) {
        float a = __half2float(hr[k]) * s2[k] + t2[k];
        acc += a * Wd1[k * 16 + j];
    }
    float r = fmaxf(acc + bd1[j], 0.0f);
    float v = r * Wd2[j];
#pragma unroll
    for (int off = 8; off; off >>= 1) v += __shfl_down(v, off, 16);
    if (j == 0) out[row] = v + bd2[0];
}

// ---------------------------------------------------------------------------
extern "C" void kernel_launch(void* const* d_in, const int* in_sizes, int n_in,
                              void* d_out, int out_size, void* d_ws, size_t ws_size,
                              hipStream_t stream)
{
    const float* x   = (const float*)d_in[0];
    const float* Wx1 = (const float*)d_in[1];
    const float* Wh1 = (const float*)d_in[2];
    const float* b1  = (const float*)d_in[3];
    const float* g1  = (const float*)d_in[4];
    const float* be1 = (const float*)d_in[5];
    const float* Wx2 = (const float*)d_in[6];
    const float* Wh2 = (const float*)d_in[7];
    const float* b2  = (const float*)d_in[8];
    const float* g2  = (const float*)d_in[9];
    const float* be2 = (const float*)d_in[10];
    const float* Wd1 = (const float*)d_in[11];
    const float* bd1 = (const float*)d_in[12];
    const float* Wd2 = (const float*)d_in[13];
    const float* bd2 = (const float*)d_in[14];
    float* out = (float*)d_out;

    char* ws = (char*)d_ws;
    __half* xW    = (__half*)(ws);                   // 128 MiB  [B*T, 2048]
    __half* h1    = (__half*)(ws + 134217728);       // 32 MiB   [B*T, 512]
    __half* h2    = (__half*)(ws + 167772160);       // 32 MiB (contiguous after h1)
    float*  accum = (float*) (ws + 201326592);       // 2048 f32
    float*  s1    = (float*) (ws + 201334784);
    float*  t1    = s1 + HH;
    float*  s2    = t1 + HH;
    float*  t2    = s2 + HH;

    const int M = BB * TT;  // 32768

    zero_init<<<1, 256, 0, stream>>>(accum);
    // fill h1+h2 (contiguous 64 MiB) with sentinel for write-once dataflow
    sentinel_init<<<4096, 256, 0, stream>>>((uint4*)h1, 4194304);

    gemm_mfma<false, false><<<dim3(16, M / 128), 256, 0, stream>>>(
        x, Wx1, b1, nullptr, nullptr, xW, FF);

    lstm_scan_mfma<<<32, 512, 0, stream>>>(xW, Wh1, h1, accum);
    bn_finalize<<<1, 512, 0, stream>>>(accum, g1, be1, s1, t1);

    gemm_mfma<true, true><<<dim3(16, M / 128), 256, 0, stream>>>(
        h1, Wx2, b2, s1, t1, xW, HH);

    lstm_scan_mfma<<<32, 512, 0, stream>>>(xW, Wh2, h2, accum + 1024);
    bn_finalize<<<1, 512, 0, stream>>>(accum + 1024, g2, be2, s2, t2);

    head_kernel<<<M / 16, 256, 0, stream>>>(h2, s2, t2, Wd1, bd1, Wd2, bd2, out);
}